// Round 1
// baseline (198.796 us; speedup 1.0000x reference)
//
#include <hip/hip_runtime.h>
#include <hip/hip_bf16.h>

#define NUM_VERTICES 6890
#define THRESHOLD 0.3f
#define B_DIM 8
#define V_DIM 4
#define H_DIM 512
#define W_DIM 512
#define TOTAL_PIX (V_DIM * H_DIM * W_DIM)   // 1,048,576
#define CHUNKS 32
#define BLOCK_THREADS 512

// Accumulate per-(batch, chunk) into LDS histograms, then atomic-flush into
// global partial accumulator ws layout: [B][2][NUM_VERTICES] (pred, cnt).
__global__ __launch_bounds__(BLOCK_THREADS)
void hc3d_accum_kernel(const float* __restrict__ seg,
                       const int* __restrict__ verts,
                       const float* __restrict__ bary,
                       float* __restrict__ partial) {
    __shared__ float s_pred[NUM_VERTICES];
    __shared__ float s_cnt[NUM_VERTICES];

    const int b = blockIdx.y;
    for (int i = threadIdx.x; i < NUM_VERTICES; i += BLOCK_THREADS) {
        s_pred[i] = 0.0f;
        s_cnt[i]  = 0.0f;
    }
    __syncthreads();

    const int per   = TOTAL_PIX / CHUNKS;       // 32768
    const int start = blockIdx.x * per;
    const int end   = start + per;
    const float* __restrict__ segb = seg + (size_t)b * TOTAL_PIX;

    for (int p = start + threadIdx.x; p < end; p += BLOCK_THREADS) {
        const float s = segb[p];
        const int3 v = *reinterpret_cast<const int3*>(verts + 3 * (size_t)p);
        const bool valid = ((unsigned)v.x < NUM_VERTICES) &
                           ((unsigned)v.y < NUM_VERTICES) &
                           ((unsigned)v.z < NUM_VERTICES);
        if ((s > THRESHOLD) && valid) {
            const float3 w = *reinterpret_cast<const float3*>(bary + 3 * (size_t)p);
            atomicAdd(&s_pred[v.x], w.x);
            atomicAdd(&s_pred[v.y], w.y);
            atomicAdd(&s_pred[v.z], w.z);
            atomicAdd(&s_cnt[v.x], 1.0f);
            atomicAdd(&s_cnt[v.y], 1.0f);
            atomicAdd(&s_cnt[v.z], 1.0f);
        }
    }
    __syncthreads();

    float* __restrict__ pb = partial + (size_t)b * (2 * NUM_VERTICES);
    for (int i = threadIdx.x; i < NUM_VERTICES; i += BLOCK_THREADS) {
        const float pv = s_pred[i];
        const float cv = s_cnt[i];
        if (pv != 0.0f) atomicAdd(&pb[i], pv);
        if (cv != 0.0f) atomicAdd(&pb[NUM_VERTICES + i], cv);
    }
}

__global__ __launch_bounds__(256)
void hc3d_finalize_kernel(const float* __restrict__ partial,
                          float* __restrict__ out) {
    const int idx = blockIdx.x * 256 + threadIdx.x;  // over B*NUM_VERTICES
    if (idx < B_DIM * NUM_VERTICES) {
        const int b = idx / NUM_VERTICES;
        const int v = idx - b * NUM_VERTICES;
        const float* pb = partial + (size_t)b * (2 * NUM_VERTICES);
        const float pred = pb[v];
        const float cnt  = pb[NUM_VERTICES + v];
        const float val  = (cnt > 0.0f) ? (pred / cnt) : pred;
        out[idx] = (val > THRESHOLD) ? 1.0f : 0.0f;
    }
}

extern "C" void kernel_launch(void* const* d_in, const int* in_sizes, int n_in,
                              void* d_out, int out_size, void* d_ws, size_t ws_size,
                              hipStream_t stream) {
    const float* seg   = (const float*)d_in[0];   // [B,V,H,W] f32
    const int*   verts = (const int*)d_in[1];     // [V,H,W,3] i32
    const float* bary  = (const float*)d_in[2];   // [V,H,W,3] f32
    float* out = (float*)d_out;                   // [B, NUM_VERTICES] f32
    float* partial = (float*)d_ws;                // [B][2][NUM_VERTICES] f32

    const size_t partial_bytes = (size_t)B_DIM * 2 * NUM_VERTICES * sizeof(float);
    hipMemsetAsync(partial, 0, partial_bytes, stream);

    dim3 grid(CHUNKS, B_DIM);
    hc3d_accum_kernel<<<grid, BLOCK_THREADS, 0, stream>>>(seg, verts, bary, partial);

    const int total_out = B_DIM * NUM_VERTICES;
    hc3d_finalize_kernel<<<(total_out + 255) / 256, 256, 0, stream>>>(partial, out);
}